// Round 1
// baseline (268.544 us; speedup 1.0000x reference)
//
#include <hip/hip_runtime.h>

#define IN_DIM 128
#define OUT_DIM 128
#define NUM_RELS 8
#define SCAN_ELEMS 2048   // per block, 256 thr x 8

typedef unsigned short u16;
typedef u16 u16x8 __attribute__((ext_vector_type(8)));
typedef u16 u16x4 __attribute__((ext_vector_type(4)));
typedef __bf16 bf16x8 __attribute__((ext_vector_type(8)));
typedef float f32x4 __attribute__((ext_vector_type(4)));

__device__ __forceinline__ u16 f2bf(float f) {
    unsigned u = __float_as_uint(f);
    u += 0x7FFF + ((u >> 16) & 1);      // RNE
    return (u16)(u >> 16);
}
__device__ __forceinline__ float bf2f(u16 h) {
    return __uint_as_float((unsigned)h << 16);
}

// ---------- fused prep: cast x -> bf16, build WbT [col][k] (k = rel*128+kin,
// rel 8 = self-loop weight), zero the (dst,rel) histogram ----------
__global__ __launch_bounds__(256) void k_prep(
    const float* __restrict__ x, const float* __restrict__ weight,
    const float* __restrict__ slw,
    u16* __restrict__ xb, u16* __restrict__ WbT, int* __restrict__ cursor,
    int N, int n8, int BA, int BB)
{
    const int b = blockIdx.x;
    const int tid = threadIdx.x;
    if (b < BA) {
        long i = ((long)b * 256 + tid) * 4;
        if (i < (long)N * 128) {
            float4 v = *(const float4*)(x + i);
            u16x4 o;
            o[0] = f2bf(v.x); o[1] = f2bf(v.y); o[2] = f2bf(v.z); o[3] = f2bf(v.w);
            *(u16x4*)(xb + i) = o;
        }
    } else if (b < BA + BB) {
        int i = ((b - BA) * 256 + tid) * 4;      // element idx into WbT[128][1152]
        if (i < 128 * 1152) {
            const int col = i / 1152;
            const int kk  = i - col * 1152;      // multiple of 4; 1024 boundary aligned
            u16x4 o;
            #pragma unroll
            for (int j = 0; j < 4; ++j) {
                const int kj = kk + j;
                const float f = (kj < 1024)
                    ? weight[((kj >> 7) << 14) + ((kj & 127) << 7) + col]
                    : slw[((kj - 1024) << 7) + col];
                o[j] = f2bf(f);
            }
            *(u16x4*)(WbT + i) = o;
        }
    } else {
        int i = ((b - BA - BB) * 256 + tid) * 4;
        if (i < n8) *(int4*)(cursor + i) = make_int4(0, 0, 0, 0);
    }
}

// ---------- CSR build over key = dst*8 + rel ----------
__global__ __launch_bounds__(256) void k_hist(
    const int* __restrict__ dst, const int* __restrict__ et,
    int* __restrict__ deg, int E)
{
    int e = blockIdx.x * blockDim.x + threadIdx.x;
    if (e < E) atomicAdd(&deg[(dst[e] << 3) + et[e]], 1);
}

__global__ __launch_bounds__(256) void k_scan1(
    const int* __restrict__ deg, int* __restrict__ local,
    int* __restrict__ bsum, int n)
{
    __shared__ int s[256];
    const int t = threadIdx.x;
    const int base = blockIdx.x * SCAN_ELEMS + t * 8;
    int v[8];
    int sum = 0;
    #pragma unroll
    for (int j = 0; j < 8; ++j) {
        int i = base + j;
        v[j] = (i < n) ? deg[i] : 0;
        sum += v[j];
    }
    s[t] = sum;
    __syncthreads();
    #pragma unroll
    for (int off = 1; off < 256; off <<= 1) {
        int y = (t >= off) ? s[t - off] : 0;
        __syncthreads();
        s[t] += y;
        __syncthreads();
    }
    int run = s[t] - sum;
    #pragma unroll
    for (int j = 0; j < 8; ++j) {
        int i = base + j;
        if (i < n) local[i] = run;
        run += v[j];
    }
    if (t == 255) bsum[blockIdx.x] = s[255];
}

__global__ __launch_bounds__(256) void k_scan23(
    int* __restrict__ row_ptr, const int* __restrict__ bsum,
    int* __restrict__ cursor, int B, int n)
{
    __shared__ int s[256];
    const int t = threadIdx.x;
    int v = (t < B) ? bsum[t] : 0;
    s[t] = v;
    __syncthreads();
    #pragma unroll
    for (int off = 1; off < 256; off <<= 1) {
        int y = (t >= off) ? s[t - off] : 0;
        __syncthreads();
        s[t] += y;
        __syncthreads();
    }
    const int myoff = (blockIdx.x == 0) ? 0 : s[blockIdx.x - 1];
    const int total = s[255];
    const int base = blockIdx.x * SCAN_ELEMS + t * 8;
    #pragma unroll
    for (int j = 0; j < 8; ++j) {
        int i = base + j;
        if (i < n) {
            int val = row_ptr[i] + myoff;
            row_ptr[i] = val;
            cursor[i] = val;
        }
    }
    if (blockIdx.x == 0 && t == 0) row_ptr[n] = total;
}

__global__ __launch_bounds__(256) void k_fill(
    const int* __restrict__ src, const int* __restrict__ dst,
    const int* __restrict__ et, int* __restrict__ cursor,
    int* __restrict__ packed, int E)
{
    int e = blockIdx.x * blockDim.x + threadIdx.x;
    if (e >= E) return;
    int pos = atomicAdd(&cursor[(dst[e] << 3) + et[e]], 1);
    packed[pos] = (et[e] << 17) | src[e];
}

// ---------- fused aggregate + transform + bias + relu ----------
// Per block: 64 dst nodes. Phase 1: 16-lane groups gather x[src] (bf16, small
// L2/L3-hot footprint), accumulate per-rel in fp32 regs (edges arrive sorted
// by rel thanks to the (dst,rel) CSR), flush each rel row bf16 into the LDS
// agg slab [64][1152+8]; slot 8 = x itself (self loop). Pad +8: row stride
// 2320 B = 580 dw == 4 (mod 32) -> 2-way LDS conflict (free) on ds_read_b128.
// Phase 2: 4 waves, wave w owns cols [32w,32w+32): [64x1152]@[1152x128] via
// mfma 16x16x32, B-frags = contiguous u16x8 vector loads from WbT[col][k]
// (295 KB, L2-resident). Epilogue: +bias, relu, fp32 out. hr never exists.
#define NPB 64
#define LDK 1160

__global__ __launch_bounds__(256) void fused_rgcn(
    const u16* __restrict__ xb,      // [N][128] bf16
    const u16* __restrict__ WbT,     // [128][1152] bf16 (col-major weights)
    const float* __restrict__ bias,
    const int* __restrict__ row_ptr, // [8N+1]
    const int* __restrict__ packed,  // [E]: (rel<<17)|src, grouped by (dst,rel)
    float* __restrict__ out, int N)
{
    __shared__ u16 agg[NPB][LDK];    // 148480 B

    const int tid = threadIdx.x;
    const int n0 = blockIdx.x * NPB;

    // ---------------- phase 1: gather/aggregate ----------------
    {
        const int grp = tid >> 4;          // 16 groups
        const int lo  = (tid & 15) * 8;    // 8 bf16 per lane

        for (int i = 0; i < 4; ++i) {
            const int nl = (grp << 2) + i;
            const int gn = n0 + nl;
            if (gn >= N) break;
            const int beg = row_ptr[gn << 3];
            const int end = row_ptr[(gn << 3) + 8];
            u16* arow = &agg[nl][0];
            float a0=0.f,a1=0.f,a2=0.f,a3=0.f,a4=0.f,a5=0.f,a6=0.f,a7=0.f;
            int cur = 0;

#define FLUSH_() { u16x8 o_; \
    o_[0]=f2bf(a0); o_[1]=f2bf(a1); o_[2]=f2bf(a2); o_[3]=f2bf(a3); \
    o_[4]=f2bf(a4); o_[5]=f2bf(a5); o_[6]=f2bf(a6); o_[7]=f2bf(a7); \
    *(u16x8*)(arow + (cur << 7) + lo) = o_; \
    a0=0.f;a1=0.f;a2=0.f;a3=0.f;a4=0.f;a5=0.f;a6=0.f;a7=0.f; }

#define PROC_(p_, v_) { const int r_ = (p_) >> 17; \
    while (cur < r_) { FLUSH_(); ++cur; } \
    a0 += bf2f((v_)[0]); a1 += bf2f((v_)[1]); a2 += bf2f((v_)[2]); a3 += bf2f((v_)[3]); \
    a4 += bf2f((v_)[4]); a5 += bf2f((v_)[5]); a6 += bf2f((v_)[6]); a7 += bf2f((v_)[7]); }

            int k = beg;
            for (; k + 4 <= end; k += 4) {
                const int p0 = packed[k],     p1 = packed[k + 1];
                const int p2 = packed[k + 2], p3 = packed[k + 3];
                const u16x8 v0 = *(const u16x8*)(xb + (size_t)(p0 & 0x1FFFF) * 128 + lo);
                const u16x8 v1 = *(const u16x8*)(xb + (size_t)(p1 & 0x1FFFF) * 128 + lo);
                const u16x8 v2 = *(const u16x8*)(xb + (size_t)(p2 & 0x1FFFF) * 128 + lo);
                const u16x8 v3 = *(const u16x8*)(xb + (size_t)(p3 & 0x1FFFF) * 128 + lo);
                PROC_(p0, v0); PROC_(p1, v1); PROC_(p2, v2); PROC_(p3, v3);
            }
            for (; k < end; ++k) {
                const int p = packed[k];
                const u16x8 v = *(const u16x8*)(xb + (size_t)(p & 0x1FFFF) * 128 + lo);
                PROC_(p, v);
            }
            while (cur < 8) { FLUSH_(); ++cur; }   // empty rels get explicit zeros
            // self-loop slot (rel 8)
            const u16x8 sv = *(const u16x8*)(xb + (size_t)gn * 128 + lo);
            *(u16x8*)(arow + 1024 + lo) = sv;
#undef PROC_
#undef FLUSH_
        }
    }
    __syncthreads();

    // ---------------- phase 2: GEMM out[64x128] = agg @ W ----------------
    const int wv = tid >> 6, lane = tid & 63;
    const int q = lane >> 4, l = lane & 15;
    const int cbase = wv << 5;                 // wave's 32-col slab
    const float bv0 = bias[cbase + l];
    const float bv1 = bias[cbase + 16 + l];

    f32x4 acc[4][2] = {};

    const u16* B0p = WbT + (size_t)(cbase + l) * 1152 + (q << 3);
    const u16* B1p = B0p + (size_t)16 * 1152;

    #pragma unroll 4
    for (int kk = 0; kk < 36; ++kk) {
        const int k0 = (kk << 5) + (q << 3);
        const bf16x8 b0 = __builtin_bit_cast(bf16x8, *(const u16x8*)(B0p + (kk << 5)));
        const bf16x8 b1 = __builtin_bit_cast(bf16x8, *(const u16x8*)(B1p + (kk << 5)));
        const bf16x8 a0 = __builtin_bit_cast(bf16x8, *(const u16x8*)(&agg[l][k0]));
        const bf16x8 a1 = __builtin_bit_cast(bf16x8, *(const u16x8*)(&agg[16 + l][k0]));
        const bf16x8 a2 = __builtin_bit_cast(bf16x8, *(const u16x8*)(&agg[32 + l][k0]));
        const bf16x8 a3 = __builtin_bit_cast(bf16x8, *(const u16x8*)(&agg[48 + l][k0]));
        acc[0][0] = __builtin_amdgcn_mfma_f32_16x16x32_bf16(a0, b0, acc[0][0], 0, 0, 0);
        acc[0][1] = __builtin_amdgcn_mfma_f32_16x16x32_bf16(a0, b1, acc[0][1], 0, 0, 0);
        acc[1][0] = __builtin_amdgcn_mfma_f32_16x16x32_bf16(a1, b0, acc[1][0], 0, 0, 0);
        acc[1][1] = __builtin_amdgcn_mfma_f32_16x16x32_bf16(a1, b1, acc[1][1], 0, 0, 0);
        acc[2][0] = __builtin_amdgcn_mfma_f32_16x16x32_bf16(a2, b0, acc[2][0], 0, 0, 0);
        acc[2][1] = __builtin_amdgcn_mfma_f32_16x16x32_bf16(a2, b1, acc[2][1], 0, 0, 0);
        acc[3][0] = __builtin_amdgcn_mfma_f32_16x16x32_bf16(a3, b0, acc[3][0], 0, 0, 0);
        acc[3][1] = __builtin_amdgcn_mfma_f32_16x16x32_bf16(a3, b1, acc[3][1], 0, 0, 0);
    }

    // epilogue: C layout col=lane&15, row=(lane>>4)*4+j; +bias, relu, fp32 out
    const int rbase = n0 + (q << 2);
    #pragma unroll
    for (int mt = 0; mt < 4; ++mt) {
        const int row = rbase + (mt << 4);
        #pragma unroll
        for (int j = 0; j < 4; ++j) {
            if (row + j < N) {
                float* op = out + (size_t)(row + j) * 128 + cbase + l;
                op[0]  = fmaxf(acc[mt][0][j] + bv0, 0.f);
                op[16] = fmaxf(acc[mt][1][j] + bv1, 0.f);
            }
        }
    }
}

// ---------- fp32 fallback kernels ----------
__global__ __launch_bounds__(256) void gemm128(
    const float* __restrict__ x, const float* __restrict__ W,
    const float* __restrict__ bias, float* __restrict__ out, int N)
{
    __shared__ float Ws[IN_DIM * OUT_DIM];
    __shared__ float xs[16][IN_DIM];

    const float* Wz = W + (size_t)blockIdx.z * IN_DIM * OUT_DIM;
    float* outz = out + (size_t)blockIdx.z * (size_t)N * OUT_DIM;

    {
        const float4* s4 = (const float4*)Wz;
        float4* d4 = (float4*)Ws;
        for (int i = threadIdx.x; i < IN_DIM * OUT_DIM / 4; i += 256)
            d4[i] = s4[i];
    }

    const int tid = threadIdx.x;
    const int nl = (tid >> 5) * 2;
    const int og = (tid & 31) * 4;

    float4 b4 = make_float4(0.f, 0.f, 0.f, 0.f);
    if (bias) b4 = *(const float4*)&bias[og];

    const int nchunks = (N + 15) / 16;
    for (int chunk = blockIdx.x; chunk < nchunks; chunk += gridDim.x) {
        const int n0 = chunk * 16;
        const int rows = min(16, N - n0);
        __syncthreads();
        {
            const float4* xsrc = (const float4*)(x + (size_t)n0 * IN_DIM);
            float4* xdst = (float4*)&xs[0][0];
            const int n4 = rows * (IN_DIM / 4);
            for (int i = tid; i < n4; i += 256) xdst[i] = xsrc[i];
        }
        __syncthreads();

        if (nl < rows) {
            float a00 = 0.f, a01 = 0.f, a02 = 0.f, a03 = 0.f;
            float a10 = 0.f, a11 = 0.f, a12 = 0.f, a13 = 0.f;
            #pragma unroll 8
            for (int d = 0; d < IN_DIM; ++d) {
                const float4 w4 = *(const float4*)&Ws[d * OUT_DIM + og];
                const float xa = xs[nl][d];
                const float xb = xs[nl + 1][d];
                a00 += xa * w4.x; a01 += xa * w4.y; a02 += xa * w4.z; a03 += xa * w4.w;
                a10 += xb * w4.x; a11 += xb * w4.y; a12 += xb * w4.z; a13 += xb * w4.w;
            }
            float4 r0 = make_float4(a00 + b4.x, a01 + b4.y, a02 + b4.z, a03 + b4.w);
            *(float4*)&outz[(size_t)(n0 + nl) * OUT_DIM + og] = r0;
            if (nl + 1 < rows) {
                float4 r1 = make_float4(a10 + b4.x, a11 + b4.y, a12 + b4.z, a13 + b4.w);
                *(float4*)&outz[(size_t)(n0 + nl + 1) * OUT_DIM + og] = r1;
            }
        }
    }
}

__global__ __launch_bounds__(256) void edge_direct(
    const float* __restrict__ x, const float* __restrict__ W,
    const int* __restrict__ src, const int* __restrict__ dst,
    const int* __restrict__ et, float* __restrict__ out, int E)
{
    long t = (long)blockIdx.x * blockDim.x + threadIdx.x;
    long e = t >> 6;
    int lane = (int)(t & 63);
    if (e >= E) return;
    int s = src[e], d = dst[e], r = et[e];
    const float* xr = x + (long)s * IN_DIM;
    float2 xv = *(const float2*)(xr + lane * 2);
    const float* Wr = W + (long)r * IN_DIM * OUT_DIM;
    const int o0 = lane * 2;
    float a0 = 0.f, a1 = 0.f;
    #pragma unroll 8
    for (int dd = 0; dd < 64; ++dd) {
        float xa = __shfl(xv.x, dd);
        float xb = __shfl(xv.y, dd);
        a0 += xa * Wr[(2 * dd) * OUT_DIM + o0]     + xb * Wr[(2 * dd + 1) * OUT_DIM + o0];
        a1 += xa * Wr[(2 * dd) * OUT_DIM + o0 + 1] + xb * Wr[(2 * dd + 1) * OUT_DIM + o0 + 1];
    }
    atomicAdd(out + (long)d * OUT_DIM + o0, a0);
    atomicAdd(out + (long)d * OUT_DIM + o0 + 1, a1);
}

__global__ __launch_bounds__(256) void relu_k(float* __restrict__ out, long n4)
{
    long i = (long)blockIdx.x * blockDim.x + threadIdx.x;
    if (i >= n4) return;
    float4 v = ((float4*)out)[i];
    v.x = fmaxf(v.x, 0.f); v.y = fmaxf(v.y, 0.f);
    v.z = fmaxf(v.z, 0.f); v.w = fmaxf(v.w, 0.f);
    ((float4*)out)[i] = v;
}

static inline size_t align256(size_t x) { return (x + 255) & ~(size_t)255; }

extern "C" void kernel_launch(void* const* d_in, const int* in_sizes, int n_in,
                              void* d_out, int out_size, void* d_ws, size_t ws_size,
                              hipStream_t stream)
{
    const float* x      = (const float*)d_in[0];
    const float* weight = (const float*)d_in[1];
    const float* slw    = (const float*)d_in[2];
    const float* bias   = (const float*)d_in[3];
    const int*   ei     = (const int*)d_in[4];
    const int*   et     = (const int*)d_in[5];

    const int N = in_sizes[0] / IN_DIM;
    const int E = in_sizes[5];
    const int* src  = ei;
    const int* dstp = ei + E;

    float* out = (float*)d_out;

    const int n8 = N * 8;   // CSR bins keyed (dst<<3)|rel

    // workspace layout (bf16 fused path) — no hr intermediate anymore
    size_t off = 0;
    const size_t xb_off   = off; off += align256((size_t)N * 128 * 2);
    const size_t wb_off   = off; off += align256((size_t)128 * 1152 * 2);
    const size_t rp_off   = off; off += align256((size_t)(n8 + 1) * 4);
    const size_t cur_off  = off; off += align256((size_t)n8 * 4);
    const size_t pk_off   = off; off += align256((size_t)E * 4);
    const size_t bs_off   = off; off += align256(256 * 4);
    const size_t need_bf16 = off;

    const int scanB = (n8 + SCAN_ELEMS - 1) / SCAN_ELEMS;

    if (ws_size >= need_bf16 && N <= (1 << 17) && scanB <= 256) {
        char* base   = (char*)d_ws;
        u16* xb      = (u16*)(base + xb_off);
        u16* WbT     = (u16*)(base + wb_off);
        int* row_ptr = (int*)(base + rp_off);
        int* cursor  = (int*)(base + cur_off);
        int* packed  = (int*)(base + pk_off);
        int* bsum    = (int*)(base + bs_off);

        // fused prep: cast x, build transposed weights, zero (dst,rel) histogram
        const int BA = (int)(((long)N * 128 / 4 + 255) / 256);
        const int BB = (128 * 1152 / 4 + 255) / 256;   // 144
        const int BC = (n8 / 4 + 255) / 256;
        k_prep<<<dim3(BA + BB + BC), 256, 0, stream>>>(
            x, weight, slw, xb, WbT, cursor, N, n8, BA, BB);

        // CSR over (dst,rel): edges land grouped-by-rel within each node
        k_hist<<<dim3((E + 255) / 256), 256, 0, stream>>>(dstp, et, cursor, E);
        k_scan1<<<dim3(scanB), 256, 0, stream>>>(cursor, row_ptr, bsum, n8);
        k_scan23<<<dim3(scanB), 256, 0, stream>>>(row_ptr, bsum, cursor, scanB, n8);
        k_fill<<<dim3((E + 255) / 256), 256, 0, stream>>>(src, dstp, et, cursor, packed, E);

        // single fused aggregate->transform->bias->relu kernel
        fused_rgcn<<<dim3((N + NPB - 1) / NPB), 256, 0, stream>>>(
            xb, WbT, bias, row_ptr, packed, out, N);
    } else if (ws_size >= (size_t)NUM_RELS * N * 128 * 4) {
        gemm128<<<dim3(512, 1, 1), 256, 0, stream>>>(x, slw, bias, out, N);
        long nt = (long)E * 64;
        edge_direct<<<dim3((nt + 255) / 256), 256, 0, stream>>>(x, weight, src, dstp, et, out, E);
        long n4 = (long)N * OUT_DIM / 4;
        relu_k<<<dim3((n4 + 255) / 256), 256, 0, stream>>>(out, n4);
    } else {
        gemm128<<<dim3(512, 1, 1), 256, 0, stream>>>(x, slw, bias, out, N);
        long nt = (long)E * 64;
        edge_direct<<<dim3((nt + 255) / 256), 256, 0, stream>>>(x, weight, src, dstp, et, out, E);
        long n4 = (long)N * OUT_DIM / 4;
        relu_k<<<dim3((n4 + 255) / 256), 256, 0, stream>>>(out, n4);
    }
}

// Round 2
// 251.939 us; speedup vs baseline: 1.0659x; 1.0659x over previous
//
#include <hip/hip_runtime.h>

#define IN_DIM 128
#define OUT_DIM 128
#define NUM_RELS 8
#define SCAN_ELEMS 2048   // per block, 256 thr x 8

typedef unsigned short u16;
typedef u16 u16x8 __attribute__((ext_vector_type(8)));
typedef u16 u16x4 __attribute__((ext_vector_type(4)));
typedef __bf16 bf16x8 __attribute__((ext_vector_type(8)));
typedef float f32x4 __attribute__((ext_vector_type(4)));

__device__ __forceinline__ u16 f2bf(float f) {
    unsigned u = __float_as_uint(f);
    u += 0x7FFF + ((u >> 16) & 1);      // RNE
    return (u16)(u >> 16);
}
__device__ __forceinline__ float bf2f(u16 h) {
    return __uint_as_float((unsigned)h << 16);
}

// ---------- fused prep: cast x -> bf16, build WbT [col][k] (k = rel*128+kin,
// k 1024..1151 = self-loop weight), and (dst,rel) histogram (cursor pre-zeroed
// by hipMemsetAsync on the stream) ----------
__global__ __launch_bounds__(256) void k_prep(
    const float* __restrict__ x, const float* __restrict__ weight,
    const float* __restrict__ slw,
    const int* __restrict__ dst, const int* __restrict__ et,
    u16* __restrict__ xb, u16* __restrict__ WbT, int* __restrict__ cursor,
    int N, int E, int BA, int BB)
{
    const int b = blockIdx.x;
    const int tid = threadIdx.x;
    if (b < BA) {
        long i = ((long)b * 256 + tid) * 4;
        if (i < (long)N * 128) {
            float4 v = *(const float4*)(x + i);
            u16x4 o;
            o[0] = f2bf(v.x); o[1] = f2bf(v.y); o[2] = f2bf(v.z); o[3] = f2bf(v.w);
            *(u16x4*)(xb + i) = o;
        }
    } else if (b < BA + BB) {
        int i = ((b - BA) * 256 + tid) * 4;      // element idx into WbT[128][1152]
        if (i < 128 * 1152) {
            const int col = i / 1152;
            const int kk  = i - col * 1152;      // multiple of 4; 1024 boundary aligned
            u16x4 o;
            #pragma unroll
            for (int j = 0; j < 4; ++j) {
                const int kj = kk + j;
                const float f = (kj < 1024)
                    ? weight[((kj >> 7) << 14) + ((kj & 127) << 7) + col]
                    : slw[((kj - 1024) << 7) + col];
                o[j] = f2bf(f);
            }
            *(u16x4*)(WbT + i) = o;
        }
    } else {
        int e = (b - BA - BB) * 256 + tid;
        if (e < E) atomicAdd(&cursor[(dst[e] << 3) + et[e]], 1);
    }
}

__global__ __launch_bounds__(256) void k_scan1(
    const int* __restrict__ deg, int* __restrict__ local,
    int* __restrict__ bsum, int n)
{
    __shared__ int s[256];
    const int t = threadIdx.x;
    const int base = blockIdx.x * SCAN_ELEMS + t * 8;
    int v[8];
    int sum = 0;
    #pragma unroll
    for (int j = 0; j < 8; ++j) {
        int i = base + j;
        v[j] = (i < n) ? deg[i] : 0;
        sum += v[j];
    }
    s[t] = sum;
    __syncthreads();
    #pragma unroll
    for (int off = 1; off < 256; off <<= 1) {
        int y = (t >= off) ? s[t - off] : 0;
        __syncthreads();
        s[t] += y;
        __syncthreads();
    }
    int run = s[t] - sum;
    #pragma unroll
    for (int j = 0; j < 8; ++j) {
        int i = base + j;
        if (i < n) local[i] = run;
        run += v[j];
    }
    if (t == 255) bsum[blockIdx.x] = s[255];
}

__global__ __launch_bounds__(256) void k_scan23(
    int* __restrict__ row_ptr, const int* __restrict__ bsum,
    int* __restrict__ cursor, int B, int n)
{
    __shared__ int s[256];
    const int t = threadIdx.x;
    int v = (t < B) ? bsum[t] : 0;
    s[t] = v;
    __syncthreads();
    #pragma unroll
    for (int off = 1; off < 256; off <<= 1) {
        int y = (t >= off) ? s[t - off] : 0;
        __syncthreads();
        s[t] += y;
        __syncthreads();
    }
    const int myoff = (blockIdx.x == 0) ? 0 : s[blockIdx.x - 1];
    const int total = s[255];
    const int base = blockIdx.x * SCAN_ELEMS + t * 8;
    #pragma unroll
    for (int j = 0; j < 8; ++j) {
        int i = base + j;
        if (i < n) {
            int val = row_ptr[i] + myoff;
            row_ptr[i] = val;
            cursor[i] = val;
        }
    }
    if (blockIdx.x == 0 && t == 0) row_ptr[n] = total;
}

__global__ __launch_bounds__(256) void k_fill(
    const int* __restrict__ src, const int* __restrict__ dst,
    const int* __restrict__ et, int* __restrict__ cursor,
    int* __restrict__ packed, int E)
{
    int e = blockIdx.x * blockDim.x + threadIdx.x;
    if (e >= E) return;
    int pos = atomicAdd(&cursor[(dst[e] << 3) + et[e]], 1);
    packed[pos] = (et[e] << 17) | src[e];
}

// ---------- fused aggregate + transform + bias + relu, K-CHUNKED ----------
// K=1152 split into 3 chunks of 384 (rels {0,1,2},{3,4,5},{6,7}+self).
// LDS slab 64 x 392 bf16 = 50176 B -> 3 blocks/CU (12 waves/CU) instead of
// R1's 148 KB -> 1 block/CU (the 8.8% occupancy that made R1 latency-bound).
// f32 acc[4][2] persists in VGPRs across chunks (MFMA C-in accumulates).
// Per chunk: phase1 = 16-lane groups gather x[src] (8-deep MLP) accumulating
// per-rel in fp32, flush bf16 rows into slab; barrier; phase2 = 4 waves
// K=384 MFMA sweep, B-frags = contiguous u16x8 loads from WbT (L2-hot);
// barrier; next chunk overwrites slab. Epilogue: +bias, relu, fp32 out.
#define NPB 64
#define LDK 392

__global__ __launch_bounds__(256, 3) void fused_rgcn(
    const u16* __restrict__ xb,      // [N][128] bf16
    const u16* __restrict__ WbT,     // [128][1152] bf16 (col-major weights)
    const float* __restrict__ bias,
    const int* __restrict__ row_ptr, // [8N+1]
    const int* __restrict__ packed,  // [E]: (rel<<17)|src, grouped by (dst,rel)
    float* __restrict__ out, int N)
{
    __shared__ u16 agg[NPB][LDK];    // 50176 B

    const int tid = threadIdx.x;
    const int n0 = blockIdx.x * NPB;
    const int wv = tid >> 6, lane = tid & 63;
    const int q = lane >> 4, l = lane & 15;
    const int cbase = wv << 5;
    const int grp = tid >> 4;          // 16 gather groups
    const int lo  = (tid & 15) * 8;    // 8 bf16 per lane

    f32x4 acc[4][2] = {};

    for (int ck = 0; ck < 3; ++ck) {
        const int r0 = ck * 3;
        const int r1 = (ck == 2) ? 8 : r0 + 3;

        // ---------------- phase 1: gather/aggregate this chunk's rels ----------
        for (int i = 0; i < 4; ++i) {
            const int nl = (grp << 2) + i;
            const int gn = n0 + nl;
            if (gn >= N) break;
            const int beg = row_ptr[(gn << 3) + r0];
            const int end = row_ptr[(gn << 3) + r1];
            u16* arow = &agg[nl][0];
            float a0=0.f,a1=0.f,a2=0.f,a3=0.f,a4=0.f,a5=0.f,a6=0.f,a7=0.f;
            int cur = r0;

#define FLUSH_() { u16x8 o_; \
    o_[0]=f2bf(a0); o_[1]=f2bf(a1); o_[2]=f2bf(a2); o_[3]=f2bf(a3); \
    o_[4]=f2bf(a4); o_[5]=f2bf(a5); o_[6]=f2bf(a6); o_[7]=f2bf(a7); \
    *(u16x8*)(arow + ((cur - r0) << 7) + lo) = o_; \
    a0=0.f;a1=0.f;a2=0.f;a3=0.f;a4=0.f;a5=0.f;a6=0.f;a7=0.f; }

#define PROC_(p_, v_) { const int r_ = (p_) >> 17; \
    while (cur < r_) { FLUSH_(); ++cur; } \
    a0 += bf2f((v_)[0]); a1 += bf2f((v_)[1]); a2 += bf2f((v_)[2]); a3 += bf2f((v_)[3]); \
    a4 += bf2f((v_)[4]); a5 += bf2f((v_)[5]); a6 += bf2f((v_)[6]); a7 += bf2f((v_)[7]); }

            int k = beg;
            for (; k + 8 <= end; k += 8) {
                const int p0 = packed[k],     p1 = packed[k + 1];
                const int p2 = packed[k + 2], p3 = packed[k + 3];
                const int p4 = packed[k + 4], p5 = packed[k + 5];
                const int p6 = packed[k + 6], p7 = packed[k + 7];
                const u16x8 v0 = *(const u16x8*)(xb + (size_t)(p0 & 0x1FFFF) * 128 + lo);
                const u16x8 v1 = *(const u16x8*)(xb + (size_t)(p1 & 0x1FFFF) * 128 + lo);
                const u16x8 v2 = *(const u16x8*)(xb + (size_t)(p2 & 0x1FFFF) * 128 + lo);
                const u16x8 v3 = *(const u16x8*)(xb + (size_t)(p3 & 0x1FFFF) * 128 + lo);
                const u16x8 v4 = *(const u16x8*)(xb + (size_t)(p4 & 0x1FFFF) * 128 + lo);
                const u16x8 v5 = *(const u16x8*)(xb + (size_t)(p5 & 0x1FFFF) * 128 + lo);
                const u16x8 v6 = *(const u16x8*)(xb + (size_t)(p6 & 0x1FFFF) * 128 + lo);
                const u16x8 v7 = *(const u16x8*)(xb + (size_t)(p7 & 0x1FFFF) * 128 + lo);
                PROC_(p0, v0); PROC_(p1, v1); PROC_(p2, v2); PROC_(p3, v3);
                PROC_(p4, v4); PROC_(p5, v5); PROC_(p6, v6); PROC_(p7, v7);
            }
            for (; k + 4 <= end; k += 4) {
                const int p0 = packed[k],     p1 = packed[k + 1];
                const int p2 = packed[k + 2], p3 = packed[k + 3];
                const u16x8 v0 = *(const u16x8*)(xb + (size_t)(p0 & 0x1FFFF) * 128 + lo);
                const u16x8 v1 = *(const u16x8*)(xb + (size_t)(p1 & 0x1FFFF) * 128 + lo);
                const u16x8 v2 = *(const u16x8*)(xb + (size_t)(p2 & 0x1FFFF) * 128 + lo);
                const u16x8 v3 = *(const u16x8*)(xb + (size_t)(p3 & 0x1FFFF) * 128 + lo);
                PROC_(p0, v0); PROC_(p1, v1); PROC_(p2, v2); PROC_(p3, v3);
            }
            for (; k < end; ++k) {
                const int p = packed[k];
                const u16x8 v = *(const u16x8*)(xb + (size_t)(p & 0x1FFFF) * 128 + lo);
                PROC_(p, v);
            }
            while (cur < r1) { FLUSH_(); ++cur; }   // empty rels -> explicit zeros
            if (ck == 2) {                           // self-loop row (k 256..383)
                const u16x8 sv = *(const u16x8*)(xb + (size_t)gn * 128 + lo);
                *(u16x8*)(arow + 256 + lo) = sv;
            }
#undef PROC_
#undef FLUSH_
        }
        __syncthreads();

        // ---------------- phase 2: acc += agg_chunk @ W_chunk ----------------
        const u16* B0p = WbT + (size_t)(cbase + l) * 1152 + ck * 384 + (q << 3);
        const u16* B1p = B0p + (size_t)16 * 1152;

        #pragma unroll
        for (int kk = 0; kk < 12; ++kk) {
            const int k0 = (kk << 5) + (q << 3);
            const bf16x8 b0 = __builtin_bit_cast(bf16x8, *(const u16x8*)(B0p + (kk << 5)));
            const bf16x8 b1 = __builtin_bit_cast(bf16x8, *(const u16x8*)(B1p + (kk << 5)));
            const bf16x8 a0 = __builtin_bit_cast(bf16x8, *(const u16x8*)(&agg[l][k0]));
            const bf16x8 a1 = __builtin_bit_cast(bf16x8, *(const u16x8*)(&agg[16 + l][k0]));
            const bf16x8 a2 = __builtin_bit_cast(bf16x8, *(const u16x8*)(&agg[32 + l][k0]));
            const bf16x8 a3 = __builtin_bit_cast(bf16x8, *(const u16x8*)(&agg[48 + l][k0]));
            acc[0][0] = __builtin_amdgcn_mfma_f32_16x16x32_bf16(a0, b0, acc[0][0], 0, 0, 0);
            acc[0][1] = __builtin_amdgcn_mfma_f32_16x16x32_bf16(a0, b1, acc[0][1], 0, 0, 0);
            acc[1][0] = __builtin_amdgcn_mfma_f32_16x16x32_bf16(a1, b0, acc[1][0], 0, 0, 0);
            acc[1][1] = __builtin_amdgcn_mfma_f32_16x16x32_bf16(a1, b1, acc[1][1], 0, 0, 0);
            acc[2][0] = __builtin_amdgcn_mfma_f32_16x16x32_bf16(a2, b0, acc[2][0], 0, 0, 0);
            acc[2][1] = __builtin_amdgcn_mfma_f32_16x16x32_bf16(a2, b1, acc[2][1], 0, 0, 0);
            acc[3][0] = __builtin_amdgcn_mfma_f32_16x16x32_bf16(a3, b0, acc[3][0], 0, 0, 0);
            acc[3][1] = __builtin_amdgcn_mfma_f32_16x16x32_bf16(a3, b1, acc[3][1], 0, 0, 0);
        }
        if (ck < 2) __syncthreads();   // protect slab from next chunk's phase 1
    }

    // epilogue: C layout col=lane&15, row=(lane>>4)*4+j; +bias, relu, fp32 out
    const float bv0 = bias[cbase + l];
    const float bv1 = bias[cbase + 16 + l];
    const int rbase = n0 + (q << 2);
    #pragma unroll
    for (int mt = 0; mt < 4; ++mt) {
        const int row = rbase + (mt << 4);
        #pragma unroll
        for (int j = 0; j < 4; ++j) {
            if (row + j < N) {
                float* op = out + (size_t)(row + j) * 128 + cbase + l;
                op[0]  = fmaxf(acc[mt][0][j] + bv0, 0.f);
                op[16] = fmaxf(acc[mt][1][j] + bv1, 0.f);
            }
        }
    }
}

// ---------- fp32 fallback kernels ----------
__global__ __launch_bounds__(256) void gemm128(
    const float* __restrict__ x, const float* __restrict__ W,
    const float* __restrict__ bias, float* __restrict__ out, int N)
{
    __shared__ float Ws[IN_DIM * OUT_DIM];
    __shared__ float xs[16][IN_DIM];

    const float* Wz = W + (size_t)blockIdx.z * IN_DIM * OUT_DIM;
    float* outz = out + (size_t)blockIdx.z * (size_t)N * OUT_DIM;

    {
        const float4* s4 = (const float4*)Wz;
        float4* d4 = (float4*)Ws;
        for (int i = threadIdx.x; i < IN_DIM * OUT_DIM / 4; i += 256)
            d4[i] = s4[i];
    }

    const int tid = threadIdx.x;
    const int nl = (tid >> 5) * 2;
    const int og = (tid & 31) * 4;

    float4 b4 = make_float4(0.f, 0.f, 0.f, 0.f);
    if (bias) b4 = *(const float4*)&bias[og];

    const int nchunks = (N + 15) / 16;
    for (int chunk = blockIdx.x; chunk < nchunks; chunk += gridDim.x) {
        const int n0 = chunk * 16;
        const int rows = min(16, N - n0);
        __syncthreads();
        {
            const float4* xsrc = (const float4*)(x + (size_t)n0 * IN_DIM);
            float4* xdst = (float4*)&xs[0][0];
            const int n4 = rows * (IN_DIM / 4);
            for (int i = tid; i < n4; i += 256) xdst[i] = xsrc[i];
        }
        __syncthreads();

        if (nl < rows) {
            float a00 = 0.f, a01 = 0.f, a02 = 0.f, a03 = 0.f;
            float a10 = 0.f, a11 = 0.f, a12 = 0.f, a13 = 0.f;
            #pragma unroll 8
            for (int d = 0; d < IN_DIM; ++d) {
                const float4 w4 = *(const float4*)&Ws[d * OUT_DIM + og];
                const float xa = xs[nl][d];
                const float xb = xs[nl + 1][d];
                a00 += xa * w4.x; a01 += xa * w4.y; a02 += xa * w4.z; a03 += xa * w4.w;
                a10 += xb * w4.x; a11 += xb * w4.y; a12 += xb * w4.z; a13 += xb * w4.w;
            }
            float4 r0 = make_float4(a00 + b4.x, a01 + b4.y, a02 + b4.z, a03 + b4.w);
            *(float4*)&outz[(size_t)(n0 + nl) * OUT_DIM + og] = r0;
            if (nl + 1 < rows) {
                float4 r1 = make_float4(a10 + b4.x, a11 + b4.y, a12 + b4.z, a13 + b4.w);
                *(float4*)&outz[(size_t)(n0 + nl + 1) * OUT_DIM + og] = r1;
            }
        }
    }
}

__global__ __launch_bounds__(256) void edge_direct(
    const float* __restrict__ x, const float* __restrict__ W,
    const int* __restrict__ src, const int* __restrict__ dst,
    const int* __restrict__ et, float* __restrict__ out, int E)
{
    long t = (long)blockIdx.x * blockDim.x + threadIdx.x;
    long e = t >> 6;
    int lane = (int)(t & 63);
    if (e >= E) return;
    int s = src[e], d = dst[e], r = et[e];
    const float* xr = x + (long)s * IN_DIM;
    float2 xv = *(const float2*)(xr + lane * 2);
    const float* Wr = W + (long)r * IN_DIM * OUT_DIM;
    const int o0 = lane * 2;
    float a0 = 0.f, a1 = 0.f;
    #pragma unroll 8
    for (int dd = 0; dd < 64; ++dd) {
        float xa = __shfl(xv.x, dd);
        float xb = __shfl(xv.y, dd);
        a0 += xa * Wr[(2 * dd) * OUT_DIM + o0]     + xb * Wr[(2 * dd + 1) * OUT_DIM + o0];
        a1 += xa * Wr[(2 * dd) * OUT_DIM + o0 + 1] + xb * Wr[(2 * dd + 1) * OUT_DIM + o0 + 1];
    }
    atomicAdd(out + (long)d * OUT_DIM + o0, a0);
    atomicAdd(out + (long)d * OUT_DIM + o0 + 1, a1);
}

__global__ __launch_bounds__(256) void relu_k(float* __restrict__ out, long n4)
{
    long i = (long)blockIdx.x * blockDim.x + threadIdx.x;
    if (i >= n4) return;
    float4 v = ((float4*)out)[i];
    v.x = fmaxf(v.x, 0.f); v.y = fmaxf(v.y, 0.f);
    v.z = fmaxf(v.z, 0.f); v.w = fmaxf(v.w, 0.f);
    ((float4*)out)[i] = v;
}

static inline size_t align256(size_t x) { return (x + 255) & ~(size_t)255; }

extern "C" void kernel_launch(void* const* d_in, const int* in_sizes, int n_in,
                              void* d_out, int out_size, void* d_ws, size_t ws_size,
                              hipStream_t stream)
{
    const float* x      = (const float*)d_in[0];
    const float* weight = (const float*)d_in[1];
    const float* slw    = (const float*)d_in[2];
    const float* bias   = (const float*)d_in[3];
    const int*   ei     = (const int*)d_in[4];
    const int*   et     = (const int*)d_in[5];

    const int N = in_sizes[0] / IN_DIM;
    const int E = in_sizes[5];
    const int* src  = ei;
    const int* dstp = ei + E;

    float* out = (float*)d_out;

    const int n8 = N * 8;   // CSR bins keyed (dst<<3)|rel

    // workspace layout (bf16 fused path)
    size_t off = 0;
    const size_t xb_off   = off; off += align256((size_t)N * 128 * 2);
    const size_t wb_off   = off; off += align256((size_t)128 * 1152 * 2);
    const size_t rp_off   = off; off += align256((size_t)(n8 + 1) * 4);
    const size_t cur_off  = off; off += align256((size_t)n8 * 4);
    const size_t pk_off   = off; off += align256((size_t)E * 4);
    const size_t bs_off   = off; off += align256(256 * 4);
    const size_t need_bf16 = off;

    const int scanB = (n8 + SCAN_ELEMS - 1) / SCAN_ELEMS;

    if (ws_size >= need_bf16 && N <= (1 << 17) && scanB <= 256) {
        char* base   = (char*)d_ws;
        u16* xb      = (u16*)(base + xb_off);
        u16* WbT     = (u16*)(base + wb_off);
        int* row_ptr = (int*)(base + rp_off);
        int* cursor  = (int*)(base + cur_off);
        int* packed  = (int*)(base + pk_off);
        int* bsum    = (int*)(base + bs_off);

        // zero (dst,rel) histogram, then fused prep: cast x, build WbT, hist
        hipMemsetAsync(cursor, 0, (size_t)n8 * sizeof(int), stream);
        const int BA = (int)(((long)N * 128 / 4 + 255) / 256);
        const int BB = (128 * 1152 / 4 + 255) / 256;   // 144
        const int BD = (E + 255) / 256;
        k_prep<<<dim3(BA + BB + BD), 256, 0, stream>>>(
            x, weight, slw, dstp, et, xb, WbT, cursor, N, E, BA, BB);

        // CSR over (dst,rel): edges land grouped-by-rel within each node
        k_scan1<<<dim3(scanB), 256, 0, stream>>>(cursor, row_ptr, bsum, n8);
        k_scan23<<<dim3(scanB), 256, 0, stream>>>(row_ptr, bsum, cursor, scanB, n8);
        k_fill<<<dim3((E + 255) / 256), 256, 0, stream>>>(src, dstp, et, cursor, packed, E);

        // single fused aggregate->transform->bias->relu kernel
        fused_rgcn<<<dim3((N + NPB - 1) / NPB), 256, 0, stream>>>(
            xb, WbT, bias, row_ptr, packed, out, N);
    } else if (ws_size >= (size_t)NUM_RELS * N * 128 * 4) {
        gemm128<<<dim3(512, 1, 1), 256, 0, stream>>>(x, slw, bias, out, N);
        long nt = (long)E * 64;
        edge_direct<<<dim3((nt + 255) / 256), 256, 0, stream>>>(x, weight, src, dstp, et, out, E);
        long n4 = (long)N * OUT_DIM / 4;
        relu_k<<<dim3((n4 + 255) / 256), 256, 0, stream>>>(out, n4);
    } else {
        gemm128<<<dim3(512, 1, 1), 256, 0, stream>>>(x, slw, bias, out, N);
        long nt = (long)E * 64;
        edge_direct<<<dim3((nt + 255) / 256), 256, 0, stream>>>(x, weight, src, dstp, et, out, E);
        long n4 = (long)N * OUT_DIM / 4;
        relu_k<<<dim3((n4 + 255) / 256), 256, 0, stream>>>(out, n4);
    }
}

// Round 3
// 225.207 us; speedup vs baseline: 1.1924x; 1.1187x over previous
//
#include <hip/hip_runtime.h>

#define IN_DIM 128
#define OUT_DIM 128
#define NUM_RELS 8
#define SCAN_ELEMS 2048   // per block, 256 thr x 8

typedef unsigned short u16;
typedef u16 u16x8 __attribute__((ext_vector_type(8)));
typedef u16 u16x4 __attribute__((ext_vector_type(4)));
typedef __bf16 bf16x8 __attribute__((ext_vector_type(8)));
typedef float f32x4 __attribute__((ext_vector_type(4)));

__device__ __forceinline__ u16 f2bf(float f) {
    unsigned u = __float_as_uint(f);
    u += 0x7FFF + ((u >> 16) & 1);      // RNE
    return (u16)(u >> 16);
}
__device__ __forceinline__ float bf2f(u16 h) {
    return __uint_as_float((unsigned)h << 16);
}

// ---------- fused prep: cast x -> bf16, build WbT [col][k] (k = rel*128+kin,
// k 1024..1151 = self-loop weight), and (dst,rel) histogram (cursor pre-zeroed
// by hipMemsetAsync on the stream) ----------
__global__ __launch_bounds__(256) void k_prep(
    const float* __restrict__ x, const float* __restrict__ weight,
    const float* __restrict__ slw,
    const int* __restrict__ dst, const int* __restrict__ et,
    u16* __restrict__ xb, u16* __restrict__ WbT, int* __restrict__ cursor,
    int N, int E, int BA, int BB)
{
    const int b = blockIdx.x;
    const int tid = threadIdx.x;
    if (b < BA) {
        long i = ((long)b * 256 + tid) * 4;
        if (i < (long)N * 128) {
            float4 v = *(const float4*)(x + i);
            u16x4 o;
            o[0] = f2bf(v.x); o[1] = f2bf(v.y); o[2] = f2bf(v.z); o[3] = f2bf(v.w);
            *(u16x4*)(xb + i) = o;
        }
    } else if (b < BA + BB) {
        int i = ((b - BA) * 256 + tid) * 4;      // element idx into WbT[128][1152]
        if (i < 128 * 1152) {
            const int col = i / 1152;
            const int kk  = i - col * 1152;      // multiple of 4; 1024 boundary aligned
            u16x4 o;
            #pragma unroll
            for (int j = 0; j < 4; ++j) {
                const int kj = kk + j;
                const float f = (kj < 1024)
                    ? weight[((kj >> 7) << 14) + ((kj & 127) << 7) + col]
                    : slw[((kj - 1024) << 7) + col];
                o[j] = f2bf(f);
            }
            *(u16x4*)(WbT + i) = o;
        }
    } else {
        int e = (b - BA - BB) * 256 + tid;
        if (e < E) atomicAdd(&cursor[(dst[e] << 3) + et[e]], 1);
    }
}

__global__ __launch_bounds__(256) void k_scan1(
    const int* __restrict__ deg, int* __restrict__ local,
    int* __restrict__ bsum, int n)
{
    __shared__ int s[256];
    const int t = threadIdx.x;
    const int base = blockIdx.x * SCAN_ELEMS + t * 8;
    int v[8];
    int sum = 0;
    #pragma unroll
    for (int j = 0; j < 8; ++j) {
        int i = base + j;
        v[j] = (i < n) ? deg[i] : 0;
        sum += v[j];
    }
    s[t] = sum;
    __syncthreads();
    #pragma unroll
    for (int off = 1; off < 256; off <<= 1) {
        int y = (t >= off) ? s[t - off] : 0;
        __syncthreads();
        s[t] += y;
        __syncthreads();
    }
    int run = s[t] - sum;
    #pragma unroll
    for (int j = 0; j < 8; ++j) {
        int i = base + j;
        if (i < n) local[i] = run;
        run += v[j];
    }
    if (t == 255) bsum[blockIdx.x] = s[255];
}

__global__ __launch_bounds__(256) void k_scan23(
    int* __restrict__ row_ptr, const int* __restrict__ bsum,
    int* __restrict__ cursor, int B, int n)
{
    __shared__ int s[256];
    const int t = threadIdx.x;
    int v = (t < B) ? bsum[t] : 0;
    s[t] = v;
    __syncthreads();
    #pragma unroll
    for (int off = 1; off < 256; off <<= 1) {
        int y = (t >= off) ? s[t - off] : 0;
        __syncthreads();
        s[t] += y;
        __syncthreads();
    }
    const int myoff = (blockIdx.x == 0) ? 0 : s[blockIdx.x - 1];
    const int total = s[255];
    const int base = blockIdx.x * SCAN_ELEMS + t * 8;
    #pragma unroll
    for (int j = 0; j < 8; ++j) {
        int i = base + j;
        if (i < n) {
            int val = row_ptr[i] + myoff;
            row_ptr[i] = val;
            cursor[i] = val;
        }
    }
    if (blockIdx.x == 0 && t == 0) row_ptr[n] = total;
}

__global__ __launch_bounds__(256) void k_fill(
    const int* __restrict__ src, const int* __restrict__ dst,
    const int* __restrict__ et, int* __restrict__ cursor,
    int* __restrict__ packed, int E)
{
    int e = blockIdx.x * blockDim.x + threadIdx.x;
    if (e >= E) return;
    int pos = atomicAdd(&cursor[(dst[e] << 3) + et[e]], 1);
    packed[pos] = (et[e] << 17) | src[e];
}

// ---------- fused aggregate + transform + bias + relu ----------
// R3: latency-chain fix. 32 nodes/block, 512 threads = 32 gather groups ->
// exactly ONE node per group per chunk (R2 serialized 4 nodes/group; with
// ~3.75 edges per (node,chunk) that was a chain of short dependent loads).
// LDS 32x392x2 = 25088 B; __launch_bounds__(512,8) -> 4 blocks/CU = 32
// waves/CU (vs R2's measured 19%). 128 concurrent gather chains per CU.
// Phase 2: 8 waves x (32 rows x 16 cols), K=384/chunk, acc f32x4[2] persists
// across the 3 chunks. WbT stays global (295 KB, per-XCD-L2-resident).
#define NPB 32
#define LDK 392

__global__ __launch_bounds__(512, 8) void fused_rgcn(
    const u16* __restrict__ xb,      // [N][128] bf16
    const u16* __restrict__ WbT,     // [128][1152] bf16 (col-major weights)
    const float* __restrict__ bias,
    const int* __restrict__ row_ptr, // [8N+1]
    const int* __restrict__ packed,  // [E]: (rel<<17)|src, grouped by (dst,rel)
    float* __restrict__ out, int N)
{
    __shared__ u16 agg[NPB][LDK];    // 25088 B

    const int tid = threadIdx.x;
    const int n0 = blockIdx.x * NPB;
    const int lane = tid & 63;
    const int wv = tid >> 6;           // 0..7
    const int q = lane >> 4, l = lane & 15;
    const int cbase = wv << 4;         // wave's 16-col slab
    const int grp = tid >> 4;          // 0..31 gather groups, 1 node each
    const int lo  = (tid & 15) * 8;    // 8 bf16 per lane

    const int gn = n0 + grp;
    u16* arow = &agg[grp][0];

    f32x4 acc[2] = {};

    for (int ck = 0; ck < 3; ++ck) {
        const int r0 = ck * 3;
        const int r1 = (ck == 2) ? 8 : r0 + 3;

        // ---------------- phase 1: gather/aggregate (1 node per group) --------
        if (gn < N) {
            const int beg = row_ptr[(gn << 3) + r0];
            const int end = row_ptr[(gn << 3) + r1];
            float a0=0.f,a1=0.f,a2=0.f,a3=0.f,a4=0.f,a5=0.f,a6=0.f,a7=0.f;
            int cur = r0;

#define FLUSH_() { u16x8 o_; \
    o_[0]=f2bf(a0); o_[1]=f2bf(a1); o_[2]=f2bf(a2); o_[3]=f2bf(a3); \
    o_[4]=f2bf(a4); o_[5]=f2bf(a5); o_[6]=f2bf(a6); o_[7]=f2bf(a7); \
    *(u16x8*)(arow + ((cur - r0) << 7) + lo) = o_; \
    a0=0.f;a1=0.f;a2=0.f;a3=0.f;a4=0.f;a5=0.f;a6=0.f;a7=0.f; }

#define PROC_(p_, v_) { const int r_ = (p_) >> 17; \
    while (cur < r_) { FLUSH_(); ++cur; } \
    a0 += bf2f((v_)[0]); a1 += bf2f((v_)[1]); a2 += bf2f((v_)[2]); a3 += bf2f((v_)[3]); \
    a4 += bf2f((v_)[4]); a5 += bf2f((v_)[5]); a6 += bf2f((v_)[6]); a7 += bf2f((v_)[7]); }

            int k = beg;
            for (; k + 4 <= end; k += 4) {
                const int p0 = packed[k],     p1 = packed[k + 1];
                const int p2 = packed[k + 2], p3 = packed[k + 3];
                const u16x8 v0 = *(const u16x8*)(xb + ((size_t)(p0 & 0x1FFFF) << 7) + lo);
                const u16x8 v1 = *(const u16x8*)(xb + ((size_t)(p1 & 0x1FFFF) << 7) + lo);
                const u16x8 v2 = *(const u16x8*)(xb + ((size_t)(p2 & 0x1FFFF) << 7) + lo);
                const u16x8 v3 = *(const u16x8*)(xb + ((size_t)(p3 & 0x1FFFF) << 7) + lo);
                PROC_(p0, v0); PROC_(p1, v1); PROC_(p2, v2); PROC_(p3, v3);
            }
            for (; k < end; ++k) {
                const int p = packed[k];
                const u16x8 v = *(const u16x8*)(xb + ((size_t)(p & 0x1FFFF) << 7) + lo);
                PROC_(p, v);
            }
            while (cur < r1) { FLUSH_(); ++cur; }   // empty rels -> explicit zeros
            if (ck == 2) {                           // self-loop row (k 256..383)
                const u16x8 sv = *(const u16x8*)(xb + ((size_t)gn << 7) + lo);
                *(u16x8*)(arow + 256 + lo) = sv;
            }
#undef PROC_
#undef FLUSH_
        }
        __syncthreads();

        // ---------------- phase 2: acc += agg_chunk @ W_chunk ----------------
        const u16* Bp = WbT + (size_t)(cbase + l) * 1152 + ck * 384 + (q << 3);
        #pragma unroll
        for (int kk = 0; kk < 12; ++kk) {
            const int k0 = (kk << 5) + (q << 3);
            const bf16x8 b  = __builtin_bit_cast(bf16x8, *(const u16x8*)(Bp + (kk << 5)));
            const bf16x8 a0 = __builtin_bit_cast(bf16x8, *(const u16x8*)(&agg[l][k0]));
            const bf16x8 a1 = __builtin_bit_cast(bf16x8, *(const u16x8*)(&agg[16 + l][k0]));
            acc[0] = __builtin_amdgcn_mfma_f32_16x16x32_bf16(a0, b, acc[0], 0, 0, 0);
            acc[1] = __builtin_amdgcn_mfma_f32_16x16x32_bf16(a1, b, acc[1], 0, 0, 0);
        }
        if (ck < 2) __syncthreads();   // protect slab from next chunk's phase 1
    }

    // epilogue: C layout col=lane&15, row=(lane>>4)*4+j; +bias, relu, fp32 out
    const float bv = bias[cbase + l];
    #pragma unroll
    for (int m = 0; m < 2; ++m) {
        const int rbase = n0 + (m << 4) + (q << 2);
        #pragma unroll
        for (int j = 0; j < 4; ++j) {
            const int row = rbase + j;
            if (row < N)
                out[(size_t)row * 128 + cbase + l] = fmaxf(acc[m][j] + bv, 0.f);
        }
    }
}

// ---------- fp32 fallback kernels ----------
__global__ __launch_bounds__(256) void gemm128(
    const float* __restrict__ x, const float* __restrict__ W,
    const float* __restrict__ bias, float* __restrict__ out, int N)
{
    __shared__ float Ws[IN_DIM * OUT_DIM];
    __shared__ float xs[16][IN_DIM];

    const float* Wz = W + (size_t)blockIdx.z * IN_DIM * OUT_DIM;
    float* outz = out + (size_t)blockIdx.z * (size_t)N * OUT_DIM;

    {
        const float4* s4 = (const float4*)Wz;
        float4* d4 = (float4*)Ws;
        for (int i = threadIdx.x; i < IN_DIM * OUT_DIM / 4; i += 256)
            d4[i] = s4[i];
    }

    const int tid = threadIdx.x;
    const int nl = (tid >> 5) * 2;
    const int og = (tid & 31) * 4;

    float4 b4 = make_float4(0.f, 0.f, 0.f, 0.f);
    if (bias) b4 = *(const float4*)&bias[og];

    const int nchunks = (N + 15) / 16;
    for (int chunk = blockIdx.x; chunk < nchunks; chunk += gridDim.x) {
        const int n0 = chunk * 16;
        const int rows = min(16, N - n0);
        __syncthreads();
        {
            const float4* xsrc = (const float4*)(x + (size_t)n0 * IN_DIM);
            float4* xdst = (float4*)&xs[0][0];
            const int n4 = rows * (IN_DIM / 4);
            for (int i = tid; i < n4; i += 256) xdst[i] = xsrc[i];
        }
        __syncthreads();

        if (nl < rows) {
            float a00 = 0.f, a01 = 0.f, a02 = 0.f, a03 = 0.f;
            float a10 = 0.f, a11 = 0.f, a12 = 0.f, a13 = 0.f;
            #pragma unroll 8
            for (int d = 0; d < IN_DIM; ++d) {
                const float4 w4 = *(const float4*)&Ws[d * OUT_DIM + og];
                const float xa = xs[nl][d];
                const float xb = xs[nl + 1][d];
                a00 += xa * w4.x; a01 += xa * w4.y; a02 += xa * w4.z; a03 += xa * w4.w;
                a10 += xb * w4.x; a11 += xb * w4.y; a12 += xb * w4.z; a13 += xb * w4.w;
            }
            float4 r0 = make_float4(a00 + b4.x, a01 + b4.y, a02 + b4.z, a03 + b4.w);
            *(float4*)&outz[(size_t)(n0 + nl) * OUT_DIM + og] = r0;
            if (nl + 1 < rows) {
                float4 r1 = make_float4(a10 + b4.x, a11 + b4.y, a12 + b4.z, a13 + b4.w);
                *(float4*)&outz[(size_t)(n0 + nl + 1) * OUT_DIM + og] = r1;
            }
        }
    }
}

__global__ __launch_bounds__(256) void edge_direct(
    const float* __restrict__ x, const float* __restrict__ W,
    const int* __restrict__ src, const int* __restrict__ dst,
    const int* __restrict__ et, float* __restrict__ out, int E)
{
    long t = (long)blockIdx.x * blockDim.x + threadIdx.x;
    long e = t >> 6;
    int lane = (int)(t & 63);
    if (e >= E) return;
    int s = src[e], d = dst[e], r = et[e];
    const float* xr = x + (long)s * IN_DIM;
    float2 xv = *(const float2*)(xr + lane * 2);
    const float* Wr = W + (long)r * IN_DIM * OUT_DIM;
    const int o0 = lane * 2;
    float a0 = 0.f, a1 = 0.f;
    #pragma unroll 8
    for (int dd = 0; dd < 64; ++dd) {
        float xa = __shfl(xv.x, dd);
        float xb = __shfl(xv.y, dd);
        a0 += xa * Wr[(2 * dd) * OUT_DIM + o0]     + xb * Wr[(2 * dd + 1) * OUT_DIM + o0];
        a1 += xa * Wr[(2 * dd) * OUT_DIM + o0 + 1] + xb * Wr[(2 * dd + 1) * OUT_DIM + o0 + 1];
    }
    atomicAdd(out + (long)d * OUT_DIM + o0, a0);
    atomicAdd(out + (long)d * OUT_DIM + o0 + 1, a1);
}

__global__ __launch_bounds__(256) void relu_k(float* __restrict__ out, long n4)
{
    long i = (long)blockIdx.x * blockDim.x + threadIdx.x;
    if (i >= n4) return;
    float4 v = ((float4*)out)[i];
    v.x = fmaxf(v.x, 0.f); v.y = fmaxf(v.y, 0.f);
    v.z = fmaxf(v.z, 0.f); v.w = fmaxf(v.w, 0.f);
    ((float4*)out)[i] = v;
}

static inline size_t align256(size_t x) { return (x + 255) & ~(size_t)255; }

extern "C" void kernel_launch(void* const* d_in, const int* in_sizes, int n_in,
                              void* d_out, int out_size, void* d_ws, size_t ws_size,
                              hipStream_t stream)
{
    const float* x      = (const float*)d_in[0];
    const float* weight = (const float*)d_in[1];
    const float* slw    = (const float*)d_in[2];
    const float* bias   = (const float*)d_in[3];
    const int*   ei     = (const int*)d_in[4];
    const int*   et     = (const int*)d_in[5];

    const int N = in_sizes[0] / IN_DIM;
    const int E = in_sizes[5];
    const int* src  = ei;
    const int* dstp = ei + E;

    float* out = (float*)d_out;

    const int n8 = N * 8;   // CSR bins keyed (dst<<3)|rel

    // workspace layout (bf16 fused path)
    size_t off = 0;
    const size_t xb_off   = off; off += align256((size_t)N * 128 * 2);
    const size_t wb_off   = off; off += align256((size_t)128 * 1152 * 2);
    const size_t rp_off   = off; off += align256((size_t)(n8 + 1) * 4);
    const size_t cur_off  = off; off += align256((size_t)n8 * 4);
    const size_t pk_off   = off; off += align256((size_t)E * 4);
    const size_t bs_off   = off; off += align256(256 * 4);
    const size_t need_bf16 = off;

    const int scanB = (n8 + SCAN_ELEMS - 1) / SCAN_ELEMS;

    if (ws_size >= need_bf16 && N <= (1 << 17) && scanB <= 256) {
        char* base   = (char*)d_ws;
        u16* xb      = (u16*)(base + xb_off);
        u16* WbT     = (u16*)(base + wb_off);
        int* row_ptr = (int*)(base + rp_off);
        int* cursor  = (int*)(base + cur_off);
        int* packed  = (int*)(base + pk_off);
        int* bsum    = (int*)(base + bs_off);

        // zero (dst,rel) histogram, then fused prep: cast x, build WbT, hist
        hipMemsetAsync(cursor, 0, (size_t)n8 * sizeof(int), stream);
        const int BA = (int)(((long)N * 128 / 4 + 255) / 256);
        const int BB = (128 * 1152 / 4 + 255) / 256;   // 144
        const int BD = (E + 255) / 256;
        k_prep<<<dim3(BA + BB + BD), 256, 0, stream>>>(
            x, weight, slw, dstp, et, xb, WbT, cursor, N, E, BA, BB);

        // CSR over (dst,rel): edges land grouped-by-rel within each node
        k_scan1<<<dim3(scanB), 256, 0, stream>>>(cursor, row_ptr, bsum, n8);
        k_scan23<<<dim3(scanB), 256, 0, stream>>>(row_ptr, bsum, cursor, scanB, n8);
        k_fill<<<dim3((E + 255) / 256), 256, 0, stream>>>(src, dstp, et, cursor, packed, E);

        // single fused aggregate->transform->bias->relu kernel
        fused_rgcn<<<dim3((N + NPB - 1) / NPB), 512, 0, stream>>>(
            xb, WbT, bias, row_ptr, packed, out, N);
    } else if (ws_size >= (size_t)NUM_RELS * N * 128 * 4) {
        gemm128<<<dim3(512, 1, 1), 256, 0, stream>>>(x, slw, bias, out, N);
        long nt = (long)E * 64;
        edge_direct<<<dim3((nt + 255) / 256), 256, 0, stream>>>(x, weight, src, dstp, et, out, E);
        long n4 = (long)N * OUT_DIM / 4;
        relu_k<<<dim3((n4 + 255) / 256), 256, 0, stream>>>(out, n4);
    } else {
        gemm128<<<dim3(512, 1, 1), 256, 0, stream>>>(x, slw, bias, out, N);
        long nt = (long)E * 64;
        edge_direct<<<dim3((nt + 255) / 256), 256, 0, stream>>>(x, weight, src, dstp, et, out, E);
        long n4 = (long)N * OUT_DIM / 4;
        relu_k<<<dim3((n4 + 255) / 256), 256, 0, stream>>>(out, n4);
    }
}